// Round 2
// baseline (741.703 us; speedup 1.0000x reference)
//
#include <hip/hip_runtime.h>

#define NNODES 100000
#define NEDGES 600000
#define D 128

// ---------------------------------------------------------------------------
// Edge aggregation: one pass over edges feeds both directions.
//   sum_f[dst] += x[src], cnt_f[dst]++   (forward conv mean)
//   sum_b[src] += x[dst], cnt_b[src]++   (backward conv mean)
// 128 threads per edge (one float each), 2 edges per 256-thread block.
// Edge indices arrive as int32 (harness converts int64 -> int32).
// ---------------------------------------------------------------------------
__global__ __launch_bounds__(256) void edge_aggregate(
    const float* __restrict__ x, const int* __restrict__ ei,
    float* __restrict__ sum_f, float* __restrict__ sum_b,
    float* __restrict__ cnt_f, float* __restrict__ cnt_b)
{
    int t = blockIdx.x * 256 + threadIdx.x;
    int e = t >> 7;
    int f = t & 127;
    if (e >= NEDGES) return;
    int s = ei[e];            // edge_index[0][e]
    int d = ei[NEDGES + e];   // edge_index[1][e]
    // defensive clamp: a bad index should show as wrong values, not a fault
    s = min(max(s, 0), NNODES - 1);
    d = min(max(d, 0), NNODES - 1);
    float xs = x[(size_t)s * D + f];
    float xd = x[(size_t)d * D + f];
    atomicAdd(&sum_f[(size_t)d * D + f], xs);
    atomicAdd(&sum_b[(size_t)s * D + f], xd);
    if (f == 0) {
        atomicAdd(&cnt_f[d], 1.0f);
        atomicAdd(&cnt_b[s], 1.0f);
    }
}

// ---------------------------------------------------------------------------
// Fused GEMM + bias + relu:
// out = relu(0.5*( mean_f@wl_f^T + mean_b@wl_b^T + x@(wr_f+wr_b)^T + bl_f+bl_b ))
// Treated as A[N,384] @ W[384,128] with A = [sum_f*rcp | sum_b*rcp | x].
// sum_f lives in d_out; each block reads its own rows (seg 0) before the
// epilogue overwrites them -- no cross-block hazard.
// Tile: 128 rows x 128 cols per block, BK=16, 256 threads, 8x8 per thread.
// ---------------------------------------------------------------------------
__global__ __launch_bounds__(256) void gemm_fused(
    const float* __restrict__ x,
    const float* __restrict__ sum_f, const float* __restrict__ sum_b,
    const float* __restrict__ cnt_f, const float* __restrict__ cnt_b,
    const float* __restrict__ wl_f, const float* __restrict__ wl_b,
    const float* __restrict__ wr_f, const float* __restrict__ wr_b,
    const float* __restrict__ bl_f, const float* __restrict__ bl_b,
    float* __restrict__ out)
{
    __shared__ float As[16][128];   // As[kk][m] = A[(n0+m)][k0+kk] * scale
    __shared__ float Bs[16][128];   // Bs[kk][o] = W[o][k0+kk]

    const int tid = threadIdx.x;
    const int n0 = blockIdx.x * 128;
    const int tc = tid & 15;   // col group: cols tc*8 .. tc*8+7
    const int tr = tid >> 4;   // row group: rows tr*8 .. tr*8+7

    float acc[8][8];
#pragma unroll
    for (int i = 0; i < 8; ++i)
#pragma unroll
        for (int j = 0; j < 8; ++j) acc[i][j] = 0.0f;

    const int lm = tid >> 2;        // 0..63 (row / weight-row for staging)
    const int lk = (tid & 3) * 4;   // 0,4,8,12 (k sub-offset, float4)

    for (int seg = 0; seg < 3; ++seg) {
        const float* __restrict__ A  = (seg == 0) ? sum_f : (seg == 1) ? sum_b : x;
        const float* __restrict__ C  = (seg == 0) ? cnt_f : (seg == 1) ? cnt_b : nullptr;
        const float* __restrict__ W0 = (seg == 0) ? wl_f  : (seg == 1) ? wl_b  : wr_f;
        const float* __restrict__ W1 = (seg == 2) ? wr_b  : nullptr;

        for (int k0 = 0; k0 < D; k0 += 16) {
            __syncthreads();
            // stage A (transposed into [kk][m])
#pragma unroll
            for (int it = 0; it < 2; ++it) {
                int m = lm + it * 64;
                int row = n0 + m;
                float4 v = make_float4(0.f, 0.f, 0.f, 0.f);
                float scale = 1.0f;
                if (row < NNODES) {
                    v = *(const float4*)(A + (size_t)row * D + k0 + lk);
                    if (C) scale = 1.0f / fmaxf(C[row], 1.0f);
                }
                As[lk + 0][m] = v.x * scale;
                As[lk + 1][m] = v.y * scale;
                As[lk + 2][m] = v.z * scale;
                As[lk + 3][m] = v.w * scale;
            }
            // stage B (transposed weights; seg 2 sums wr_f + wr_b)
#pragma unroll
            for (int it = 0; it < 2; ++it) {
                int o = lm + it * 64;
                float4 w = *(const float4*)(W0 + (size_t)o * D + k0 + lk);
                if (W1) {
                    float4 w2 = *(const float4*)(W1 + (size_t)o * D + k0 + lk);
                    w.x += w2.x; w.y += w2.y; w.z += w2.z; w.w += w2.w;
                }
                Bs[lk + 0][o] = w.x;
                Bs[lk + 1][o] = w.y;
                Bs[lk + 2][o] = w.z;
                Bs[lk + 3][o] = w.w;
            }
            __syncthreads();
#pragma unroll
            for (int kk = 0; kk < 16; ++kk) {
                float a[8], b[8];
                *(float4*)&a[0] = *(const float4*)&As[kk][tr * 8];
                *(float4*)&a[4] = *(const float4*)&As[kk][tr * 8 + 4];
                *(float4*)&b[0] = *(const float4*)&Bs[kk][tc * 8];
                *(float4*)&b[4] = *(const float4*)&Bs[kk][tc * 8 + 4];
#pragma unroll
                for (int i = 0; i < 8; ++i)
#pragma unroll
                    for (int j = 0; j < 8; ++j)
                        acc[i][j] = fmaf(a[i], b[j], acc[i][j]);
            }
        }
    }

    // epilogue: 0.5*(acc + bias), relu, store
    float bias[8];
#pragma unroll
    for (int j = 0; j < 8; ++j) {
        int c = tc * 8 + j;
        bias[j] = bl_f[c] + bl_b[c];
    }
#pragma unroll
    for (int i = 0; i < 8; ++i) {
        int row = n0 + tr * 8 + i;
        if (row >= NNODES) continue;
        float vals[8];
#pragma unroll
        for (int j = 0; j < 8; ++j) {
            float v = 0.5f * (acc[i][j] + bias[j]);
            vals[j] = v > 0.f ? v : 0.f;
        }
        *(float4*)(out + (size_t)row * D + tc * 8)     = make_float4(vals[0], vals[1], vals[2], vals[3]);
        *(float4*)(out + (size_t)row * D + tc * 8 + 4) = make_float4(vals[4], vals[5], vals[6], vals[7]);
    }
}

extern "C" void kernel_launch(void* const* d_in, const int* in_sizes, int n_in,
                              void* d_out, int out_size, void* d_ws, size_t ws_size,
                              hipStream_t stream)
{
    const float* x  = (const float*)d_in[0];
    const int*   ei = (const int*)d_in[1];   // int64 in reference -> int32 here
    // d_in[2] (reverse_edge_index) is flip(edge_index); one pass over ei covers both.
    const float* wl_f = (const float*)d_in[3];
    const float* bl_f = (const float*)d_in[4];
    const float* wr_f = (const float*)d_in[5];
    const float* wl_b = (const float*)d_in[6];
    const float* bl_b = (const float*)d_in[7];
    const float* wr_b = (const float*)d_in[8];
    float* out = (float*)d_out;

    // sum_f lives in d_out (51.2 MB); d_ws holds sum_b + counts (~52 MB).
    float* sum_f = out;
    float* sum_b = (float*)d_ws;
    float* cnt_f = sum_b + (size_t)NNODES * D;
    float* cnt_b = cnt_f + NNODES;

    hipMemsetAsync(out, 0, (size_t)NNODES * D * sizeof(float), stream);
    hipMemsetAsync(d_ws, 0,
                   ((size_t)NNODES * D + 2 * (size_t)NNODES) * sizeof(float),
                   stream);

    dim3 eb(256);
    dim3 eg(((size_t)NEDGES * 128 + 255) / 256);
    edge_aggregate<<<eg, eb, 0, stream>>>(x, ei, sum_f, sum_b, cnt_f, cnt_b);

    dim3 gb(256);
    dim3 gg((NNODES + 127) / 128);
    gemm_fused<<<gg, gb, 0, stream>>>(x, sum_f, sum_b, cnt_f, cnt_b,
                                      wl_f, wl_b, wr_f, wr_b, bl_f, bl_b, out);
}

// Round 3
// 414.987 us; speedup vs baseline: 1.7873x; 1.7873x over previous
//
#include <hip/hip_runtime.h>

#define NNODES 100000
#define NEDGES 600000
#define D 128
#define SCAN_BLOCKS 98   // ceil(100000/1024)

// ---------------------------------------------------------------------------
// CSR build, step 1: degree histogram (int atomics, 2 per edge).
// deg_f[d] = #edges into d (forward mean), deg_b[s] = #edges out of s.
// ---------------------------------------------------------------------------
__global__ __launch_bounds__(256) void k_hist(
    const int* __restrict__ ei, int* __restrict__ deg_f, int* __restrict__ deg_b)
{
    int e = blockIdx.x * 256 + threadIdx.x;
    if (e >= NEDGES) return;
    int s = ei[e];
    int d = ei[NEDGES + e];
    s = min(max(s, 0), NNODES - 1);
    d = min(max(d, 0), NNODES - 1);
    atomicAdd(&deg_f[d], 1);
    atomicAdd(&deg_b[s], 1);
}

// ---------------------------------------------------------------------------
// CSR build, step 2a: per-block exclusive scan (1024 elems/block, 2 dirs on y).
// ---------------------------------------------------------------------------
__global__ __launch_bounds__(1024) void k_scan_local(
    const int* __restrict__ deg_f, const int* __restrict__ deg_b,
    int* __restrict__ rs_f, int* __restrict__ rs_b, int* __restrict__ bsum)
{
    __shared__ int sh[1024];
    const int dir = blockIdx.y;
    const int* deg = dir ? deg_b : deg_f;
    int* rs = dir ? rs_b : rs_f;
    int i = blockIdx.x * 1024 + threadIdx.x;
    int v = (i < NNODES) ? deg[i] : 0;
    sh[threadIdx.x] = v;
    __syncthreads();
    for (int off = 1; off < 1024; off <<= 1) {
        int t = (threadIdx.x >= off) ? sh[threadIdx.x - off] : 0;
        __syncthreads();
        sh[threadIdx.x] += t;
        __syncthreads();
    }
    int incl = sh[threadIdx.x];
    if (i < NNODES) rs[i] = incl - v;                 // exclusive, block-local
    if (threadIdx.x == 1023) bsum[dir * SCAN_BLOCKS + blockIdx.x] = incl;
}

// ---------------------------------------------------------------------------
// CSR build, step 2b: exclusive scan of the 2x98 block sums (segmented).
// ---------------------------------------------------------------------------
__global__ __launch_bounds__(256) void k_scan_bsums(int* __restrict__ bsum)
{
    __shared__ int sh[256];
    int t = threadIdx.x;
    if (t < 2 * SCAN_BLOCKS) sh[t] = bsum[t];
    __syncthreads();
    if (t == 0) {
        int run = 0;
        for (int b = 0; b < SCAN_BLOCKS; ++b) { int v = sh[b]; sh[b] = run; run += v; }
        run = 0;
        for (int b = SCAN_BLOCKS; b < 2 * SCAN_BLOCKS; ++b) { int v = sh[b]; sh[b] = run; run += v; }
    }
    __syncthreads();
    if (t < 2 * SCAN_BLOCKS) bsum[t] = sh[t];
}

// ---------------------------------------------------------------------------
// CSR build, step 2c: add block offsets; init scatter cursors; seal rs[N].
// ---------------------------------------------------------------------------
__global__ __launch_bounds__(1024) void k_scan_add(
    int* __restrict__ rs_f, int* __restrict__ rs_b,
    int* __restrict__ cur_f, int* __restrict__ cur_b, const int* __restrict__ bsum)
{
    const int dir = blockIdx.y;
    int i = blockIdx.x * 1024 + threadIdx.x;
    int* rs  = dir ? rs_b : rs_f;
    int* cur = dir ? cur_b : cur_f;
    if (i < NNODES) {
        int v = rs[i] + bsum[dir * SCAN_BLOCKS + blockIdx.x];
        rs[i] = v;
        cur[i] = v;
    }
    if (i == 0) { rs_f[NNODES] = NEDGES; rs_b[NNODES] = NEDGES; }
}

// ---------------------------------------------------------------------------
// CSR build, step 3: scatter edge endpoints into grouped adjacency lists.
// csr_f (grouped by dst) holds src ids; csr_b (grouped by src) holds dst ids.
// ---------------------------------------------------------------------------
__global__ __launch_bounds__(256) void k_scatter(
    const int* __restrict__ ei, int* __restrict__ cur_f, int* __restrict__ cur_b,
    int* __restrict__ csr_f, int* __restrict__ csr_b)
{
    int e = blockIdx.x * 256 + threadIdx.x;
    if (e >= NEDGES) return;
    int s = ei[e];
    int d = ei[NEDGES + e];
    s = min(max(s, 0), NNODES - 1);
    d = min(max(d, 0), NNODES - 1);
    int pf = atomicAdd(&cur_f[d], 1);
    if (pf >= 0 && pf < NEDGES) csr_f[pf] = s;
    int pb = atomicAdd(&cur_b[s], 1);
    if (pb >= 0 && pb < NEDGES) csr_b[pb] = d;
}

// ---------------------------------------------------------------------------
// Gather-reduce means: one 32-lane group per (node, direction); lane owns a
// float4 column chunk. deg from row-start deltas; pre-divided mean stored.
// ---------------------------------------------------------------------------
__global__ __launch_bounds__(256) void k_mean(
    const float* __restrict__ x,
    const int* __restrict__ rs_f, const int* __restrict__ csr_f,
    const int* __restrict__ rs_b, const int* __restrict__ csr_b,
    float* __restrict__ mean_f, float* __restrict__ mean_b)
{
    int g = (blockIdx.x * 256 + threadIdx.x) >> 5;
    int lane = threadIdx.x & 31;
    if (g >= 2 * NNODES) return;
    const int dir = (g >= NNODES);
    const int n = dir ? g - NNODES : g;
    const int* rs  = dir ? rs_b : rs_f;
    const int* csr = dir ? csr_b : csr_f;
    float* dst = dir ? mean_b : mean_f;
    int b0 = rs[n], b1 = rs[n + 1];
    b0 = min(max(b0, 0), NEDGES);
    b1 = min(max(b1, b0), NEDGES);
    float4 acc = make_float4(0.f, 0.f, 0.f, 0.f);
    for (int j = b0; j < b1; ++j) {
        int nbr = csr[j];
        float4 v = *(const float4*)(x + (size_t)nbr * D + lane * 4);
        acc.x += v.x; acc.y += v.y; acc.z += v.z; acc.w += v.w;
    }
    float sc = 1.0f / (float)max(b1 - b0, 1);
    acc.x *= sc; acc.y *= sc; acc.z *= sc; acc.w *= sc;
    *(float4*)(dst + (size_t)n * D + lane * 4) = acc;
}

// ---------------------------------------------------------------------------
// Fused GEMM + bias + relu:
// out = relu(0.5*( mean_f@wl_f^T + mean_b@wl_b^T + x@(wr_f+wr_b)^T + bl_f+bl_b ))
// A[N,384] @ W[384,128]; A = [mean_f | mean_b | x] (means pre-divided).
// mean_f lives in d_out; each block reads only its own rows in seg 0, before
// its epilogue write -- no cross-block hazard.
// ---------------------------------------------------------------------------
__global__ __launch_bounds__(256) void gemm_fused(
    const float* __restrict__ x,
    const float* __restrict__ mean_f, const float* __restrict__ mean_b,
    const float* __restrict__ wl_f, const float* __restrict__ wl_b,
    const float* __restrict__ wr_f, const float* __restrict__ wr_b,
    const float* __restrict__ bl_f, const float* __restrict__ bl_b,
    float* __restrict__ out)
{
    __shared__ float As[16][128];
    __shared__ float Bs[16][128];

    const int tid = threadIdx.x;
    const int n0 = blockIdx.x * 128;
    const int tc = tid & 15;
    const int tr = tid >> 4;

    float acc[8][8];
#pragma unroll
    for (int i = 0; i < 8; ++i)
#pragma unroll
        for (int j = 0; j < 8; ++j) acc[i][j] = 0.0f;

    const int lm = tid >> 2;
    const int lk = (tid & 3) * 4;

    for (int seg = 0; seg < 3; ++seg) {
        const float* __restrict__ A  = (seg == 0) ? mean_f : (seg == 1) ? mean_b : x;
        const float* __restrict__ W0 = (seg == 0) ? wl_f   : (seg == 1) ? wl_b   : wr_f;
        const float* __restrict__ W1 = (seg == 2) ? wr_b   : nullptr;

        for (int k0 = 0; k0 < D; k0 += 16) {
            __syncthreads();
#pragma unroll
            for (int it = 0; it < 2; ++it) {
                int m = lm + it * 64;
                int row = n0 + m;
                float4 v = make_float4(0.f, 0.f, 0.f, 0.f);
                if (row < NNODES)
                    v = *(const float4*)(A + (size_t)row * D + k0 + lk);
                As[lk + 0][m] = v.x;
                As[lk + 1][m] = v.y;
                As[lk + 2][m] = v.z;
                As[lk + 3][m] = v.w;
            }
#pragma unroll
            for (int it = 0; it < 2; ++it) {
                int o = lm + it * 64;
                float4 w = *(const float4*)(W0 + (size_t)o * D + k0 + lk);
                if (W1) {
                    float4 w2 = *(const float4*)(W1 + (size_t)o * D + k0 + lk);
                    w.x += w2.x; w.y += w2.y; w.z += w2.z; w.w += w2.w;
                }
                Bs[lk + 0][o] = w.x;
                Bs[lk + 1][o] = w.y;
                Bs[lk + 2][o] = w.z;
                Bs[lk + 3][o] = w.w;
            }
            __syncthreads();
#pragma unroll
            for (int kk = 0; kk < 16; ++kk) {
                float a[8], b[8];
                *(float4*)&a[0] = *(const float4*)&As[kk][tr * 8];
                *(float4*)&a[4] = *(const float4*)&As[kk][tr * 8 + 4];
                *(float4*)&b[0] = *(const float4*)&Bs[kk][tc * 8];
                *(float4*)&b[4] = *(const float4*)&Bs[kk][tc * 8 + 4];
#pragma unroll
                for (int i = 0; i < 8; ++i)
#pragma unroll
                    for (int j = 0; j < 8; ++j)
                        acc[i][j] = fmaf(a[i], b[j], acc[i][j]);
            }
        }
    }

    float bias[8];
#pragma unroll
    for (int j = 0; j < 8; ++j) {
        int c = tc * 8 + j;
        bias[j] = bl_f[c] + bl_b[c];
    }
#pragma unroll
    for (int i = 0; i < 8; ++i) {
        int row = n0 + tr * 8 + i;
        if (row >= NNODES) continue;
        float vals[8];
#pragma unroll
        for (int j = 0; j < 8; ++j) {
            float v = 0.5f * (acc[i][j] + bias[j]);
            vals[j] = v > 0.f ? v : 0.f;
        }
        *(float4*)(out + (size_t)row * D + tc * 8)     = make_float4(vals[0], vals[1], vals[2], vals[3]);
        *(float4*)(out + (size_t)row * D + tc * 8 + 4) = make_float4(vals[4], vals[5], vals[6], vals[7]);
    }
}

extern "C" void kernel_launch(void* const* d_in, const int* in_sizes, int n_in,
                              void* d_out, int out_size, void* d_ws, size_t ws_size,
                              hipStream_t stream)
{
    const float* x  = (const float*)d_in[0];
    const int*   ei = (const int*)d_in[1];   // int64 in reference -> int32 here
    const float* wl_f = (const float*)d_in[3];
    const float* bl_f = (const float*)d_in[4];
    const float* wr_f = (const float*)d_in[5];
    const float* wl_b = (const float*)d_in[6];
    const float* bl_b = (const float*)d_in[7];
    const float* wr_b = (const float*)d_in[8];
    float* out = (float*)d_out;

    // ws layout (4B units): mean_b | deg_f | deg_b | rs_f | rs_b | cur_f |
    //                       cur_b | bsum | csr_f | csr_b        (~58.4 MB)
    float* mean_b = (float*)d_ws;
    int* p = (int*)(mean_b + (size_t)NNODES * D);
    int* deg_f = p;                 p += NNODES;
    int* deg_b = p;                 p += NNODES;
    int* rs_f  = p;                 p += NNODES + 1;
    int* rs_b  = p;                 p += NNODES + 1;
    int* cur_f = p;                 p += NNODES;
    int* cur_b = p;                 p += NNODES;
    int* bsum  = p;                 p += 2 * SCAN_BLOCKS + 2;
    int* csr_f = p;                 p += NEDGES;
    int* csr_b = p;
    float* mean_f = out;            // reused by gemm per-block before epilogue

    hipMemsetAsync(deg_f, 0, 2 * (size_t)NNODES * sizeof(int), stream);

    dim3 b256(256), b1024(1024);
    dim3 gE((NEDGES + 255) / 256);
    dim3 gScan(SCAN_BLOCKS, 2);

    k_hist<<<gE, b256, 0, stream>>>(ei, deg_f, deg_b);
    k_scan_local<<<gScan, b1024, 0, stream>>>(deg_f, deg_b, rs_f, rs_b, bsum);
    k_scan_bsums<<<1, b256, 0, stream>>>(bsum);
    k_scan_add<<<gScan, b1024, 0, stream>>>(rs_f, rs_b, cur_f, cur_b, bsum);
    k_scatter<<<gE, b256, 0, stream>>>(ei, cur_f, cur_b, csr_f, csr_b);

    dim3 gMean((2 * NNODES * 32 + 255) / 256);
    k_mean<<<gMean, b256, 0, stream>>>(x, rs_f, csr_f, rs_b, csr_b, mean_f, mean_b);

    dim3 gG((NNODES + 127) / 128);
    gemm_fused<<<gG, b256, 0, stream>>>(x, mean_f, mean_b,
                                        wl_f, wl_b, wr_f, wr_b, bl_f, bl_b, out);
}

// Round 4
// 289.868 us; speedup vs baseline: 2.5588x; 1.4316x over previous
//
#include <hip/hip_runtime.h>

#define NNODES 100000
#define NEDGES 600000
#define D 128
#define SCAN_BLOCKS 98   // ceil(100000/1024)

typedef short bf16x8 __attribute__((ext_vector_type(8)));
typedef float f32x4  __attribute__((ext_vector_type(4)));

__device__ __forceinline__ unsigned short f2bf(float f) {
    unsigned u = __float_as_uint(f);
    unsigned r = (u + 0x7FFFu + ((u >> 16) & 1u)) >> 16;
    return (unsigned short)r;
}
__device__ __forceinline__ float bf2f(unsigned short h) {
    return __uint_as_float(((unsigned)h) << 16);
}

// ---------------------------------------------------------------------------
// x (fp32) -> xb (bf16). 4 elems/thread.
// ---------------------------------------------------------------------------
__global__ __launch_bounds__(256) void k_tobf16(
    const float* __restrict__ x, unsigned short* __restrict__ xb)
{
    int i = blockIdx.x * 256 + threadIdx.x;      // float4 index
    if (i >= NNODES * D / 4) return;
    float4 v = *(const float4*)(x + (size_t)i * 4);
    ushort4 o;
    o.x = f2bf(v.x); o.y = f2bf(v.y); o.z = f2bf(v.z); o.w = f2bf(v.w);
    *(ushort4*)(xb + (size_t)i * 4) = o;
}

// ---------------------------------------------------------------------------
// Weight prep: wcat[0]=wl_f, wcat[1]=wl_b, wcat[2]=wr_f+wr_b (bf16, row-major
// [out_c][in_k]); bb = bl_f + bl_b (fp32).
// ---------------------------------------------------------------------------
__global__ __launch_bounds__(256) void k_wprep(
    const float* __restrict__ wl_f, const float* __restrict__ wl_b,
    const float* __restrict__ wr_f, const float* __restrict__ wr_b,
    const float* __restrict__ bl_f, const float* __restrict__ bl_b,
    unsigned short* __restrict__ wcat, float* __restrict__ bb)
{
    int i = blockIdx.x * 256 + threadIdx.x;
    if (i >= 128 * 128) return;
    wcat[i]             = f2bf(wl_f[i]);
    wcat[16384 + i]     = f2bf(wl_b[i]);
    wcat[32768 + i]     = f2bf(wr_f[i] + wr_b[i]);
    if (i < 128) bb[i] = bl_f[i] + bl_b[i];
}

// ---------------------------------------------------------------------------
// CSR build (unchanged from round 3): hist -> scan -> scatter.
// ---------------------------------------------------------------------------
__global__ __launch_bounds__(256) void k_hist(
    const int* __restrict__ ei, int* __restrict__ deg_f, int* __restrict__ deg_b)
{
    int e = blockIdx.x * 256 + threadIdx.x;
    if (e >= NEDGES) return;
    int s = ei[e];
    int d = ei[NEDGES + e];
    s = min(max(s, 0), NNODES - 1);
    d = min(max(d, 0), NNODES - 1);
    atomicAdd(&deg_f[d], 1);
    atomicAdd(&deg_b[s], 1);
}

__global__ __launch_bounds__(1024) void k_scan_local(
    const int* __restrict__ deg_f, const int* __restrict__ deg_b,
    int* __restrict__ rs_f, int* __restrict__ rs_b, int* __restrict__ bsum)
{
    __shared__ int sh[1024];
    const int dir = blockIdx.y;
    const int* deg = dir ? deg_b : deg_f;
    int* rs = dir ? rs_b : rs_f;
    int i = blockIdx.x * 1024 + threadIdx.x;
    int v = (i < NNODES) ? deg[i] : 0;
    sh[threadIdx.x] = v;
    __syncthreads();
    for (int off = 1; off < 1024; off <<= 1) {
        int t = (threadIdx.x >= off) ? sh[threadIdx.x - off] : 0;
        __syncthreads();
        sh[threadIdx.x] += t;
        __syncthreads();
    }
    int incl = sh[threadIdx.x];
    if (i < NNODES) rs[i] = incl - v;
    if (threadIdx.x == 1023) bsum[dir * SCAN_BLOCKS + blockIdx.x] = incl;
}

__global__ __launch_bounds__(256) void k_scan_bsums(int* __restrict__ bsum)
{
    __shared__ int sh[256];
    int t = threadIdx.x;
    if (t < 2 * SCAN_BLOCKS) sh[t] = bsum[t];
    __syncthreads();
    if (t == 0) {
        int run = 0;
        for (int b = 0; b < SCAN_BLOCKS; ++b) { int v = sh[b]; sh[b] = run; run += v; }
        run = 0;
        for (int b = SCAN_BLOCKS; b < 2 * SCAN_BLOCKS; ++b) { int v = sh[b]; sh[b] = run; run += v; }
    }
    __syncthreads();
    if (t < 2 * SCAN_BLOCKS) bsum[t] = sh[t];
}

__global__ __launch_bounds__(1024) void k_scan_add(
    int* __restrict__ rs_f, int* __restrict__ rs_b,
    int* __restrict__ cur_f, int* __restrict__ cur_b, const int* __restrict__ bsum)
{
    const int dir = blockIdx.y;
    int i = blockIdx.x * 1024 + threadIdx.x;
    int* rs  = dir ? rs_b : rs_f;
    int* cur = dir ? cur_b : cur_f;
    if (i < NNODES) {
        int v = rs[i] + bsum[dir * SCAN_BLOCKS + blockIdx.x];
        rs[i] = v;
        cur[i] = v;
    }
    if (i == 0) { rs_f[NNODES] = NEDGES; rs_b[NNODES] = NEDGES; }
}

__global__ __launch_bounds__(256) void k_scatter(
    const int* __restrict__ ei, int* __restrict__ cur_f, int* __restrict__ cur_b,
    int* __restrict__ csr_f, int* __restrict__ csr_b)
{
    int e = blockIdx.x * 256 + threadIdx.x;
    if (e >= NEDGES) return;
    int s = ei[e];
    int d = ei[NEDGES + e];
    s = min(max(s, 0), NNODES - 1);
    d = min(max(d, 0), NNODES - 1);
    int pf = atomicAdd(&cur_f[d], 1);
    if (pf >= 0 && pf < NEDGES) csr_f[pf] = s;
    int pb = atomicAdd(&cur_b[s], 1);
    if (pb >= 0 && pb < NEDGES) csr_b[pb] = d;
}

// ---------------------------------------------------------------------------
// Gather-reduce means over bf16 x. One 32-lane group per (node, dir); lane
// owns 4 columns (8B). Writes bf16 means interleaved into d_out:
//   meanpair[n] = { mean_f[n] (256B) , mean_b[n] (256B) }
// ---------------------------------------------------------------------------
__global__ __launch_bounds__(256) void k_mean(
    const unsigned short* __restrict__ xb,
    const int* __restrict__ rs_f, const int* __restrict__ csr_f,
    const int* __restrict__ rs_b, const int* __restrict__ csr_b,
    unsigned short* __restrict__ meanpair)   // [N][256] bf16
{
    int g = (blockIdx.x * 256 + threadIdx.x) >> 5;
    int lane = threadIdx.x & 31;
    if (g >= 2 * NNODES) return;
    const int dir = (g >= NNODES);
    const int n = dir ? g - NNODES : g;
    const int* rs  = dir ? rs_b : rs_f;
    const int* csr = dir ? csr_b : csr_f;
    int b0 = rs[n], b1 = rs[n + 1];
    b0 = min(max(b0, 0), NEDGES);
    b1 = min(max(b1, b0), NEDGES);
    float a0 = 0.f, a1 = 0.f, a2 = 0.f, a3 = 0.f;
    for (int j = b0; j < b1; ++j) {
        int nbr = csr[j];
        ushort4 v = *(const ushort4*)(xb + (size_t)nbr * D + lane * 4);
        a0 += bf2f(v.x); a1 += bf2f(v.y); a2 += bf2f(v.z); a3 += bf2f(v.w);
    }
    float sc = 1.0f / (float)max(b1 - b0, 1);
    ushort4 o;
    o.x = f2bf(a0 * sc); o.y = f2bf(a1 * sc); o.z = f2bf(a2 * sc); o.w = f2bf(a3 * sc);
    *(ushort4*)(meanpair + (size_t)n * 256 + dir * 128 + lane * 4) = o;
}

// ---------------------------------------------------------------------------
// MFMA GEMM + bias + relu.
// out[N,128] = relu(0.5*( A @ Wcat^T-concat + bb )), A k-segs:
//   seg0 = mean_f (bf16, in d_out), seg1 = mean_b (bf16, in d_out), seg2 = xb.
// 128x128 tile / block, 4 waves (2x2 of 64x64), 16x16x32 bf16 MFMA, BK=64.
// LDS XOR-swizzle (byte ^= (row&7)<<4) for conflict-free ds_read_b128.
// d_out aliasing: block reads only its own 128 rows' meanpairs (bytes
// [n0*512, n0*512+64KB)) and writes exactly those bytes in the epilogue.
// ---------------------------------------------------------------------------
__global__ __launch_bounds__(256) void gemm_mfma(
    const unsigned char* __restrict__ meanpair,  // [N][512B]
    const unsigned char* __restrict__ xb,        // [N][256B]
    const unsigned char* __restrict__ wcat,      // [3][128][256B]
    const float* __restrict__ bb,
    float* __restrict__ out)
{
    __shared__ uint4 As4[1024];   // 128 rows x 128B (64 bf16), swizzled
    __shared__ uint4 Ws4[1024];
    unsigned char* Asm = (unsigned char*)As4;
    unsigned char* Wsm = (unsigned char*)Ws4;

    const int tid = threadIdx.x;
    const int n0 = blockIdx.x * 128;
    const int wv = tid >> 6;
    const int wr = wv >> 1, wc = wv & 1;
    const int lane = tid & 63;
    const int l15 = lane & 15, l4 = lane >> 4;

    f32x4 acc[4][4];
#pragma unroll
    for (int i = 0; i < 4; ++i)
#pragma unroll
        for (int j = 0; j < 4; ++j)
            acc[i][j] = (f32x4){0.f, 0.f, 0.f, 0.f};

    for (int kstep = 0; kstep < 6; ++kstep) {
        const int seg  = kstep >> 1;
        const int ks0b = (kstep & 1) * 128;   // byte offset into seg's 256B k-range
        __syncthreads();
        // stage A tile: 128 rows x 128B, 1024 16B-chunks, 4/thread
#pragma unroll
        for (int t = 0; t < 4; ++t) {
            int ch  = tid + t * 256;
            int row = ch >> 3;
            int kb  = (ch & 7) << 4;
            int rowg = n0 + row;
            uint4 v = make_uint4(0u, 0u, 0u, 0u);
            if (rowg < NNODES) {
                const unsigned char* src = (seg < 2)
                    ? meanpair + (size_t)rowg * 512 + seg * 256 + ks0b + kb
                    : xb + (size_t)rowg * 256 + ks0b + kb;
                v = *(const uint4*)src;
            }
            *(uint4*)(Asm + row * 128 + (kb ^ ((row & 7) << 4))) = v;
        }
        // stage W tile: 128 c-rows x 128B
#pragma unroll
        for (int t = 0; t < 4; ++t) {
            int ch = tid + t * 256;
            int c  = ch >> 3;
            int kb = (ch & 7) << 4;
            const unsigned char* src = wcat + seg * 32768 + (size_t)c * 256 + ks0b + kb;
            *(uint4*)(Wsm + c * 128 + (kb ^ ((c & 7) << 4))) = *(const uint4*)src;
        }
        __syncthreads();
        // compute: two K=32 slabs
#pragma unroll
        for (int ks = 0; ks < 2; ++ks) {
            const int kb = ks * 64 + l4 * 16;
            bf16x8 af[4], bf[4];
#pragma unroll
            for (int i = 0; i < 4; ++i) {
                int row = wr * 64 + i * 16 + l15;
                af[i] = *(const bf16x8*)(Asm + row * 128 + (kb ^ ((row & 7) << 4)));
            }
#pragma unroll
            for (int j = 0; j < 4; ++j) {
                int c = wc * 64 + j * 16 + l15;
                bf[j] = *(const bf16x8*)(Wsm + c * 128 + (kb ^ ((c & 7) << 4)));
            }
#pragma unroll
            for (int i = 0; i < 4; ++i)
#pragma unroll
                for (int j = 0; j < 4; ++j)
                    acc[i][j] = __builtin_amdgcn_mfma_f32_16x16x32_bf16(
                        af[i], bf[j], acc[i][j], 0, 0, 0);
        }
    }

    // epilogue: D-tile mapping col=lane&15, row=(lane>>4)*4+r
#pragma unroll
    for (int i = 0; i < 4; ++i) {
        int row0 = n0 + wr * 64 + i * 16 + l4 * 4;
#pragma unroll
        for (int j = 0; j < 4; ++j) {
            int col = wc * 64 + j * 16 + l15;
            float b = bb[col];
#pragma unroll
            for (int r = 0; r < 4; ++r) {
                int row = row0 + r;
                if (row < NNODES) {
                    float v = 0.5f * (acc[i][j][r] + b);
                    out[(size_t)row * 128 + col] = v > 0.f ? v : 0.f;
                }
            }
        }
    }
}

extern "C" void kernel_launch(void* const* d_in, const int* in_sizes, int n_in,
                              void* d_out, int out_size, void* d_ws, size_t ws_size,
                              hipStream_t stream)
{
    const float* x  = (const float*)d_in[0];
    const int*   ei = (const int*)d_in[1];   // int64 in reference -> int32 here
    const float* wl_f = (const float*)d_in[3];
    const float* bl_f = (const float*)d_in[4];
    const float* wr_f = (const float*)d_in[5];
    const float* wl_b = (const float*)d_in[6];
    const float* bl_b = (const float*)d_in[7];
    const float* wr_b = (const float*)d_in[8];
    float* out = (float*)d_out;

    // ws layout (~33 MB): xb | wcat | bb | deg_f | deg_b | rs_f | rs_b |
    //                     cur_f | cur_b | bsum | csr_f | csr_b
    unsigned short* xb   = (unsigned short*)d_ws;                 // N*D bf16
    unsigned short* wcat = xb + (size_t)NNODES * D;               // 3*128*128
    float* bb   = (float*)(wcat + 3 * 128 * 128);                 // 128
    int* p      = (int*)(bb + 128);
    int* deg_f = p;                 p += NNODES;
    int* deg_b = p;                 p += NNODES;
    int* rs_f  = p;                 p += NNODES + 1;
    int* rs_b  = p;                 p += NNODES + 1;
    int* cur_f = p;                 p += NNODES;
    int* cur_b = p;                 p += NNODES;
    int* bsum  = p;                 p += 2 * SCAN_BLOCKS + 2;
    int* csr_f = p;                 p += NEDGES;
    int* csr_b = p;
    unsigned short* meanpair = (unsigned short*)d_out;  // [N][256] bf16, overwritten by gemm

    hipMemsetAsync(deg_f, 0, 2 * (size_t)NNODES * sizeof(int), stream);

    dim3 b256(256), b1024(1024);
    dim3 gE((NEDGES + 255) / 256);
    dim3 gScan(SCAN_BLOCKS, 2);

    k_tobf16<<<dim3((NNODES * D / 4 + 255) / 256), b256, 0, stream>>>(x, xb);
    k_wprep<<<dim3(64), b256, 0, stream>>>(wl_f, wl_b, wr_f, wr_b, bl_f, bl_b, wcat, bb);
    k_hist<<<gE, b256, 0, stream>>>(ei, deg_f, deg_b);
    k_scan_local<<<gScan, b1024, 0, stream>>>(deg_f, deg_b, rs_f, rs_b, bsum);
    k_scan_bsums<<<1, b256, 0, stream>>>(bsum);
    k_scan_add<<<gScan, b1024, 0, stream>>>(rs_f, rs_b, cur_f, cur_b, bsum);
    k_scatter<<<gE, b256, 0, stream>>>(ei, cur_f, cur_b, csr_f, csr_b);

    dim3 gMean(((size_t)2 * NNODES * 32 + 255) / 256);
    k_mean<<<gMean, b256, 0, stream>>>(xb, rs_f, csr_f, rs_b, csr_b, meanpair);

    dim3 gG((NNODES + 127) / 128);
    gemm_mfma<<<gG, b256, 0, stream>>>((const unsigned char*)meanpair,
                                       (const unsigned char*)xb,
                                       (const unsigned char*)wcat, bb, out);
}

// Round 5
// 204.745 us; speedup vs baseline: 3.6226x; 1.4158x over previous
//
#include <hip/hip_runtime.h>

#define NNODES 100000
#define NEDGES 600000
#define D 128

typedef short bf16x8 __attribute__((ext_vector_type(8)));
typedef float f32x4  __attribute__((ext_vector_type(4)));

__device__ __forceinline__ unsigned short f2bf(float f) {
    unsigned u = __float_as_uint(f);
    unsigned r = (u + 0x7FFFu + ((u >> 16) & 1u)) >> 16;
    return (unsigned short)r;
}
__device__ __forceinline__ float bf2f(unsigned short h) {
    return __uint_as_float(((unsigned)h) << 16);
}

// ---------------------------------------------------------------------------
// x (fp32) -> xb (bf16). 4 elems/thread.
// ---------------------------------------------------------------------------
__global__ __launch_bounds__(256) void k_tobf16(
    const float* __restrict__ x, unsigned short* __restrict__ xb)
{
    int i = blockIdx.x * 256 + threadIdx.x;      // float4 index
    if (i >= NNODES * D / 4) return;
    float4 v = *(const float4*)(x + (size_t)i * 4);
    ushort4 o;
    o.x = f2bf(v.x); o.y = f2bf(v.y); o.z = f2bf(v.z); o.w = f2bf(v.w);
    *(ushort4*)(xb + (size_t)i * 4) = o;
}

// ---------------------------------------------------------------------------
// Weight prep: wcat[0]=wl_f, wcat[1]=wl_b, wcat[2]=wr_f+wr_b (bf16, row-major
// [out_c][in_k]); bb = bl_f + bl_b (fp32).
// ---------------------------------------------------------------------------
__global__ __launch_bounds__(256) void k_wprep(
    const float* __restrict__ wl_f, const float* __restrict__ wl_b,
    const float* __restrict__ wr_f, const float* __restrict__ wr_b,
    const float* __restrict__ bl_f, const float* __restrict__ bl_b,
    unsigned short* __restrict__ wcat, float* __restrict__ bb)
{
    int i = blockIdx.x * 256 + threadIdx.x;
    if (i >= 128 * 128) return;
    wcat[i]             = f2bf(wl_f[i]);
    wcat[16384 + i]     = f2bf(wl_b[i]);
    wcat[32768 + i]     = f2bf(wr_f[i] + wr_b[i]);
    if (i < 128) bb[i] = bl_f[i] + bl_b[i];
}

// ---------------------------------------------------------------------------
// Linked-list adjacency build (replaces hist+scan+scatter CSR).
//   next_f[e] = atomicExch(&head_f[dst], e)   -- chain of in-edges of dst
//   next_b[e] = atomicExch(&head_b[src], e)   -- chain of out-edges of src
// atomicExch hits the tiny L2-resident head arrays; next[] writes are
// coalesced (indexed by e). head_* pre-initialized to -1 (memset 0xFF).
// Chains are disjoint & acyclic by construction (each edge linked once/dir).
// ---------------------------------------------------------------------------
__global__ __launch_bounds__(256) void k_build(
    const int* __restrict__ ei,
    int* __restrict__ head_f, int* __restrict__ next_f,
    int* __restrict__ head_b, int* __restrict__ next_b)
{
    int e = blockIdx.x * 256 + threadIdx.x;
    if (e >= NEDGES) return;
    int s = ei[e];
    int d = ei[NEDGES + e];
    s = min(max(s, 0), NNODES - 1);
    d = min(max(d, 0), NNODES - 1);
    next_f[e] = atomicExch(&head_f[d], e);
    next_b[e] = atomicExch(&head_b[s], e);
}

// ---------------------------------------------------------------------------
// Chain-walk gather means over bf16 x. One 32-lane group per (node, dir);
// lane owns 4 columns (8B). Neighbor id comes from ei directly:
//   forward chain (grouped by dst): neighbor = ei[e]        (src)
//   backward chain (grouped by src): neighbor = ei[NEDGES+e] (dst)
// Writes bf16 means interleaved into d_out:
//   meanpair[n] = { mean_f[n] (256B) , mean_b[n] (256B) }
// ---------------------------------------------------------------------------
__global__ __launch_bounds__(256) void k_mean(
    const unsigned short* __restrict__ xb, const int* __restrict__ ei,
    const int* __restrict__ head_f, const int* __restrict__ next_f,
    const int* __restrict__ head_b, const int* __restrict__ next_b,
    unsigned short* __restrict__ meanpair)   // [N][256] bf16
{
    int g = (blockIdx.x * 256 + threadIdx.x) >> 5;
    int lane = threadIdx.x & 31;
    if (g >= 2 * NNODES) return;
    const int dir = (g >= NNODES);
    const int n = dir ? g - NNODES : g;
    const int* head = dir ? head_b : head_f;
    const int* next = dir ? next_b : next_f;
    const int* nbrs = dir ? ei + NEDGES : ei;

    float a0 = 0.f, a1 = 0.f, a2 = 0.f, a3 = 0.f;
    int cnt = 0;
    int e = head[n];
    for (int it = 0; it < NEDGES && e >= 0; ++it) {
        int nbr = nbrs[e];
        nbr = min(max(nbr, 0), NNODES - 1);
        ushort4 v = *(const ushort4*)(xb + (size_t)nbr * D + lane * 4);
        a0 += bf2f(v.x); a1 += bf2f(v.y); a2 += bf2f(v.z); a3 += bf2f(v.w);
        ++cnt;
        e = next[e];
    }
    float sc = 1.0f / (float)max(cnt, 1);
    ushort4 o;
    o.x = f2bf(a0 * sc); o.y = f2bf(a1 * sc); o.z = f2bf(a2 * sc); o.w = f2bf(a3 * sc);
    *(ushort4*)(meanpair + (size_t)n * 256 + dir * 128 + lane * 4) = o;
}

// ---------------------------------------------------------------------------
// MFMA GEMM + bias + relu (unchanged from round 4).
// out[N,128] = relu(0.5*( A @ Wcat^T-concat + bb )), A k-segs:
//   seg0 = mean_f (bf16, in d_out), seg1 = mean_b (bf16, in d_out), seg2 = xb.
// 128x128 tile / block, 4 waves (2x2 of 64x64), 16x16x32 bf16 MFMA, BK=64.
// LDS XOR-swizzle (byte ^= (row&7)<<4) for conflict-free ds_read_b128.
// d_out aliasing: block reads only its own 128 rows' meanpairs and writes
// exactly those bytes in the epilogue.
// ---------------------------------------------------------------------------
__global__ __launch_bounds__(256) void gemm_mfma(
    const unsigned char* __restrict__ meanpair,  // [N][512B]
    const unsigned char* __restrict__ xb,        // [N][256B]
    const unsigned char* __restrict__ wcat,      // [3][128][256B]
    const float* __restrict__ bb,
    float* __restrict__ out)
{
    __shared__ uint4 As4[1024];   // 128 rows x 128B (64 bf16), swizzled
    __shared__ uint4 Ws4[1024];
    unsigned char* Asm = (unsigned char*)As4;
    unsigned char* Wsm = (unsigned char*)Ws4;

    const int tid = threadIdx.x;
    const int n0 = blockIdx.x * 128;
    const int wv = tid >> 6;
    const int wr = wv >> 1, wc = wv & 1;
    const int lane = tid & 63;
    const int l15 = lane & 15, l4 = lane >> 4;

    f32x4 acc[4][4];
#pragma unroll
    for (int i = 0; i < 4; ++i)
#pragma unroll
        for (int j = 0; j < 4; ++j)
            acc[i][j] = (f32x4){0.f, 0.f, 0.f, 0.f};

    for (int kstep = 0; kstep < 6; ++kstep) {
        const int seg  = kstep >> 1;
        const int ks0b = (kstep & 1) * 128;   // byte offset into seg's 256B k-range
        __syncthreads();
        // stage A tile: 128 rows x 128B, 1024 16B-chunks, 4/thread
#pragma unroll
        for (int t = 0; t < 4; ++t) {
            int ch  = tid + t * 256;
            int row = ch >> 3;
            int kb  = (ch & 7) << 4;
            int rowg = n0 + row;
            uint4 v = make_uint4(0u, 0u, 0u, 0u);
            if (rowg < NNODES) {
                const unsigned char* src = (seg < 2)
                    ? meanpair + (size_t)rowg * 512 + seg * 256 + ks0b + kb
                    : xb + (size_t)rowg * 256 + ks0b + kb;
                v = *(const uint4*)src;
            }
            *(uint4*)(Asm + row * 128 + (kb ^ ((row & 7) << 4))) = v;
        }
        // stage W tile: 128 c-rows x 128B
#pragma unroll
        for (int t = 0; t < 4; ++t) {
            int ch = tid + t * 256;
            int c  = ch >> 3;
            int kb = (ch & 7) << 4;
            const unsigned char* src = wcat + seg * 32768 + (size_t)c * 256 + ks0b + kb;
            *(uint4*)(Wsm + c * 128 + (kb ^ ((c & 7) << 4))) = *(const uint4*)src;
        }
        __syncthreads();
        // compute: two K=32 slabs
#pragma unroll
        for (int ks = 0; ks < 2; ++ks) {
            const int kb = ks * 64 + l4 * 16;
            bf16x8 af[4], bf[4];
#pragma unroll
            for (int i = 0; i < 4; ++i) {
                int row = wr * 64 + i * 16 + l15;
                af[i] = *(const bf16x8*)(Asm + row * 128 + (kb ^ ((row & 7) << 4)));
            }
#pragma unroll
            for (int j = 0; j < 4; ++j) {
                int c = wc * 64 + j * 16 + l15;
                bf[j] = *(const bf16x8*)(Wsm + c * 128 + (kb ^ ((c & 7) << 4)));
            }
#pragma unroll
            for (int i = 0; i < 4; ++i)
#pragma unroll
                for (int j = 0; j < 4; ++j)
                    acc[i][j] = __builtin_amdgcn_mfma_f32_16x16x32_bf16(
                        af[i], bf[j], acc[i][j], 0, 0, 0);
        }
    }

    // epilogue: D-tile mapping col=lane&15, row=(lane>>4)*4+r
#pragma unroll
    for (int i = 0; i < 4; ++i) {
        int row0 = n0 + wr * 64 + i * 16 + l4 * 4;
#pragma unroll
        for (int j = 0; j < 4; ++j) {
            int col = wc * 64 + j * 16 + l15;
            float b = bb[col];
#pragma unroll
            for (int r = 0; r < 4; ++r) {
                int row = row0 + r;
                if (row < NNODES) {
                    float v = 0.5f * (acc[i][j][r] + b);
                    out[(size_t)row * 128 + col] = v > 0.f ? v : 0.f;
                }
            }
        }
    }
}

extern "C" void kernel_launch(void* const* d_in, const int* in_sizes, int n_in,
                              void* d_out, int out_size, void* d_ws, size_t ws_size,
                              hipStream_t stream)
{
    const float* x  = (const float*)d_in[0];
    const int*   ei = (const int*)d_in[1];   // int64 in reference -> int32 here
    const float* wl_f = (const float*)d_in[3];
    const float* bl_f = (const float*)d_in[4];
    const float* wr_f = (const float*)d_in[5];
    const float* wl_b = (const float*)d_in[6];
    const float* bl_b = (const float*)d_in[7];
    const float* wr_b = (const float*)d_in[8];
    float* out = (float*)d_out;

    // ws layout (~31.3 MB): xb | wcat | bb | head_f | head_b | next_f | next_b
    unsigned short* xb   = (unsigned short*)d_ws;                 // N*D bf16
    unsigned short* wcat = xb + (size_t)NNODES * D;               // 3*128*128
    float* bb   = (float*)(wcat + 3 * 128 * 128);                 // 128
    int* head_f = (int*)(bb + 128);
    int* head_b = head_f + NNODES;
    int* next_f = head_b + NNODES;
    int* next_b = next_f + NEDGES;
    unsigned short* meanpair = (unsigned short*)d_out;  // [N][256] bf16, overwritten by gemm

    // head_* = -1
    hipMemsetAsync(head_f, 0xFF, 2 * (size_t)NNODES * sizeof(int), stream);

    dim3 b256(256);
    dim3 gE((NEDGES + 255) / 256);

    k_tobf16<<<dim3((NNODES * D / 4 + 255) / 256), b256, 0, stream>>>(x, xb);
    k_wprep<<<dim3(64), b256, 0, stream>>>(wl_f, wl_b, wr_f, wr_b, bl_f, bl_b, wcat, bb);
    k_build<<<gE, b256, 0, stream>>>(ei, head_f, next_f, head_b, next_b);

    dim3 gMean(((size_t)2 * NNODES * 32 + 255) / 256);
    k_mean<<<gMean, b256, 0, stream>>>(xb, ei, head_f, next_f, head_b, next_b, meanpair);

    dim3 gG((NNODES + 127) / 128);
    gemm_mfma<<<gG, b256, 0, stream>>>((const unsigned char*)meanpair,
                                       (const unsigned char*)xb,
                                       (const unsigned char*)wcat, bb, out);
}